// Round 8
// baseline (2375.897 us; speedup 1.0000x reference)
//
#include <hip/hip_runtime.h>

#define T_SEQ 2048
#define BT    8192
#define DM    512
#define NR    8
#define NSTEP 5
#define K1    1536   // 3*D
#define H2    1024   // 2*D
#define VSZ   32000
#define HN    8192   // NR*H2

using ushort_t = unsigned short;
using bf16x8 = __attribute__((ext_vector_type(8))) __bf16;
using f32x4  = __attribute__((ext_vector_type(4))) float;

__device__ __forceinline__ ushort_t f2bf(float f) {
    union { float f; unsigned u; } v; v.f = f;
    unsigned r = v.u + 0x7FFFu + ((v.u >> 16) & 1u);
    return (ushort_t)(r >> 16);
}

__device__ __forceinline__ float bf2f(unsigned hi) {
    union { unsigned u; float f; } v; v.u = hi << 16;
    return v.f;
}

__device__ __forceinline__ void gload16(const void* g, void* l) {
    __builtin_amdgcn_global_load_lds((const __attribute__((address_space(1))) void*)g,
                                     (__attribute__((address_space(3))) void*)l, 16, 0, 0);
}

// gelu(tanh form) = x * sigmoid(x*(2.3022861 + 0.10294456*x^2))  [exact identity]
__device__ __forceinline__ float gelu_fast(float x) {
    float x2 = x * x;
    float u  = x * fmaf(x2, 0.10294456f, 2.3022861f);   // 2y*log2(e)
    float e  = exp2f(-u);
    return x * __builtin_amdgcn_rcpf(1.0f + e);
}

#define BAR()    __builtin_amdgcn_s_barrier()
#define VMCNT8() asm volatile("s_waitcnt vmcnt(8)" ::: "memory")
#define VMCNT0() asm volatile("s_waitcnt vmcnt(0)" ::: "memory")
#define LGKM0()  asm volatile("s_waitcnt lgkmcnt(0)" ::: "memory")

// transpose f32 src[z][K][N] -> bf16 dst[z*dstBatch + n*dstRow + k]
__global__ void transpose_f32_bf16(const float* __restrict__ src, ushort_t* __restrict__ dst,
                                   int K, int N, long long srcBatch, long long dstBatch, int dstRow)
{
    __shared__ float tile[32][33];
    src += (size_t)blockIdx.z * srcBatch;
    dst += (size_t)blockIdx.z * dstBatch;
    int n0 = blockIdx.x * 32, k0 = blockIdx.y * 32;
    int tx = threadIdx.x, ty = threadIdx.y;
    #pragma unroll
    for (int i = 0; i < 32; i += 8)
        tile[ty + i][tx] = src[(size_t)(k0 + ty + i) * N + (n0 + tx)];
    __syncthreads();
    #pragma unroll
    for (int i = 0; i < 32; i += 8)
        dst[(size_t)(n0 + ty + i) * dstRow + (k0 + tx)] = f2bf(tile[tx][ty + i]);
}

__global__ void embed_pos(const int* __restrict__ tokens, const float* __restrict__ emb,
                          const float* __restrict__ pos, float* __restrict__ x,
                          ushort_t* __restrict__ xbf)
{
    int row = blockIdx.x;
    int t = row & (T_SEQ - 1);
    int tok = tokens[row];
    int i = threadIdx.x;              // 256 threads * float2 = 512 floats
    float2 e = ((const float2*)(emb + (size_t)tok * DM))[i];
    float2 p = ((const float2*)(pos + (size_t)t * DM))[i];
    float2 v = make_float2(e.x + p.x, e.y + p.y);
    ((float2*)(x + (size_t)row * DM))[i] = v;
    ushort_t bb[2] = { f2bf(v.x), f2bf(v.y) };
    ((unsigned*)(xbf + (size_t)row * DM))[i] = *(const unsigned*)bb;
}

// rw[t,r] softmax + b2rw[t,d] = sum_r rw[t,r]*b2[r,d]   (step-invariant)
__global__ void rw_kernel(const float* __restrict__ gate, const float* __restrict__ selw,
                          const float* __restrict__ selb, const float* __restrict__ b2,
                          float* __restrict__ rw, float* __restrict__ b2rw)
{
    int t = blockIdx.x, lane = threadIdx.x;  // 64 lanes
    float p[NR];
    #pragma unroll
    for (int r = 0; r < NR; ++r) p[r] = 0.f;
    for (int d = lane; d < DM; d += 64) {
        float gv = gate[(size_t)t * DM + d] * 0.001f;
        const float* swr = selw + (size_t)d * NR;
        #pragma unroll
        for (int r = 0; r < NR; ++r) p[r] += gv * swr[r];
    }
    #pragma unroll
    for (int o = 32; o; o >>= 1) {
        #pragma unroll
        for (int r = 0; r < NR; ++r) p[r] += __shfl_xor(p[r], o, 64);
    }
    float mx = -1e30f;
    #pragma unroll
    for (int r = 0; r < NR; ++r) { p[r] += selb[r]; mx = fmaxf(mx, p[r]); }
    float s = 0.f;
    #pragma unroll
    for (int r = 0; r < NR; ++r) { p[r] = expf(p[r] - mx); s += p[r]; }
    float inv = 1.0f / s;
    #pragma unroll
    for (int r = 0; r < NR; ++r) p[r] *= inv;
    if (lane < NR) rw[t * NR + lane] = p[lane];
    #pragma unroll
    for (int it = 0; it < DM / 64; ++it) {
        int d = it * 64 + lane;
        float a = 0.f;
        #pragma unroll
        for (int r = 0; r < NR; ++r) a += p[r] * b2[r * DM + d];
        b2rw[(size_t)t * DM + d] = a;
    }
}

// Row-per-wave LN, 2 evp slices. MODE 0: x = LN(x + evp + b2rw)*g + b -> x f32 + xbf.
// MODE 2: v = LN(x + evp + b2rw)*g + b; xbf = bf16(LN(v)*fg + fb)  (fused final)
template<int MODE>
__global__ __launch_bounds__(256)
void ln_kernel(const float* __restrict__ xin, const ushort_t* __restrict__ evp,
               const float* __restrict__ b2rw,
               const float* __restrict__ g, const float* __restrict__ b,
               const float* __restrict__ fg, const float* __restrict__ fb,
               float* __restrict__ xout, ushort_t* __restrict__ xbf)
{
    int row = (blockIdx.x << 2) + (threadIdx.x >> 6);
    int lane = threadIdx.x & 63;
    int t = row & (T_SEQ - 1);
    int d0 = lane << 3;

    float s[8];
    {
        float4 a = *(const float4*)(xin + (size_t)row * DM + d0);
        float4 c = *(const float4*)(xin + (size_t)row * DM + d0 + 4);
        s[0]=a.x; s[1]=a.y; s[2]=a.z; s[3]=a.w; s[4]=c.x; s[5]=c.y; s[6]=c.z; s[7]=c.w;
    }
    #pragma unroll
    for (int sl = 0; sl < 2; ++sl) {
        uint4 u = *(const uint4*)(evp + ((size_t)sl * BT + row) * DM + d0);
        const unsigned w[4] = { u.x, u.y, u.z, u.w };
        #pragma unroll
        for (int j = 0; j < 4; ++j) {
            s[2*j]   += bf2f(w[j] & 0xffffu);
            s[2*j+1] += bf2f(w[j] >> 16);
        }
    }
    {
        float4 a = *(const float4*)(b2rw + (size_t)t * DM + d0);
        float4 c = *(const float4*)(b2rw + (size_t)t * DM + d0 + 4);
        s[0]+=a.x; s[1]+=a.y; s[2]+=a.z; s[3]+=a.w; s[4]+=c.x; s[5]+=c.y; s[6]+=c.z; s[7]+=c.w;
    }
    float sum = 0.f, sq = 0.f;
    #pragma unroll
    for (int j = 0; j < 8; ++j) { sum += s[j]; sq += s[j] * s[j]; }
    #pragma unroll
    for (int o = 32; o; o >>= 1) { sum += __shfl_xor(sum, o, 64); sq += __shfl_xor(sq, o, 64); }
    float mean = sum * (1.0f / DM);
    float var  = sq * (1.0f / DM) - mean * mean;
    float rstd = rsqrtf(var + 1e-5f);

    float o8[8];
    #pragma unroll
    for (int j = 0; j < 8; ++j)
        o8[j] = (s[j] - mean) * rstd * g[d0 + j] + b[d0 + j];

    if constexpr (MODE == 0) {
        float4 w0 = make_float4(o8[0], o8[1], o8[2], o8[3]);
        float4 w1 = make_float4(o8[4], o8[5], o8[6], o8[7]);
        *(float4*)(xout + (size_t)row * DM + d0) = w0;
        *(float4*)(xout + (size_t)row * DM + d0 + 4) = w1;
        ushort_t bb[8];
        #pragma unroll
        for (int j = 0; j < 8; ++j) bb[j] = f2bf(o8[j]);
        *(uint4*)(xbf + (size_t)row * DM + d0) = *(const uint4*)bb;
    } else {
        float sum2 = 0.f, sq2 = 0.f;
        #pragma unroll
        for (int j = 0; j < 8; ++j) { sum2 += o8[j]; sq2 += o8[j] * o8[j]; }
        #pragma unroll
        for (int o = 32; o; o >>= 1) { sum2 += __shfl_xor(sum2, o, 64); sq2 += __shfl_xor(sq2, o, 64); }
        float m2 = sum2 * (1.0f / DM);
        float v2 = sq2 * (1.0f / DM) - m2 * m2;
        float r2 = rsqrtf(v2 + 1e-5f);
        ushort_t bb[8];
        #pragma unroll
        for (int j = 0; j < 8; ++j)
            bb[j] = f2bf((o8[j] - m2) * r2 * fg[d0 + j] + fb[d0 + j]);
        *(uint4*)(xbf + (size_t)row * DM + d0) = *(const uint4*)bb;
    }
}

// ---------------------------------------------------------------------------
// 128x128 bf16 GEMM, 16x16x32 MFMA, BK=64, 4 waves (2x2), double-buffered
// 64 KB LDS -> 2 blocks/CU co-resident (cross-block stall overlap, m97/m114).
// Per K-tile: {16 ds_read | lgkm0 | BAR | stage(t+2)->buf[cur] | 32 MFMA |
//              vmcnt(8 steady / 0 tail) | BAR}
// Ledger: after stage(t+2) outstanding = {t+1:8, t+2:8}; vmcnt(8) retires t+1.
// Tail t=kt-2: outstanding {t+1:8} -> vmcnt(0).
// Staging into buf[cur] is safe: issued after lgkm0+BAR proves all waves'
// reads of buf[cur] retired.
// C[M,N] = A[M,K] @ Bt[N,K]^T.  AMODE 1: A = xbf[BT][512], K=1536 via row roll.
// Grid: XCD-bijective swizzle -> slice -> groups (nTmG x 1, tm-fastest).
// EPI 0: Cf[slice]=acc f32.  EPI 1: Cb=bf16(gelu(acc+b1)*rw).  EPI 2: Cb[slice]=bf16(acc).
// ---------------------------------------------------------------------------
template<int EPI, int AMODE>
__global__ __launch_bounds__(256, 2)
void gemm128(const ushort_t* __restrict__ A, const ushort_t* __restrict__ Bt,
             float* __restrict__ Cf, ushort_t* __restrict__ Cb,
             int nTmG, int gridTn, int nPerSlice, int ktiles,
             int lda, int ldb, int ldc, long long sliceC,
             const float* __restrict__ bias, const float* __restrict__ rwp)
{
    __shared__ ushort_t As[2][128 * 64];
    __shared__ ushort_t Bs[2][128 * 64];

    const int tid  = threadIdx.x;
    const int wave = tid >> 6, lane = tid & 63;
    const int wm = wave >> 1, wn = wave & 1;

    // bijective XCD swizzle (m204)
    int nwg = gridDim.x, bid = blockIdx.x;
    int qq = nwg >> 3, rr = nwg & 7, xc = bid & 7, wi = bid >> 3;
    int wgid = (xc < rr ? xc * (qq + 1) : rr * (qq + 1) + (xc - rr) * qq) + wi;
    int slice = wgid / nPerSlice, rem = wgid - slice * nPerSlice;
    int g = rem / nTmG, li = rem - g * nTmG;
    int gTn = g % gridTn, gTm = g / gridTn;
    int tm = gTm * nTmG + li;
    int tn = gTn;

    const int rowBase = tm * 128, colBase = tn * 128;
    const int kbase = slice * ktiles;
    if (EPI == 0) Cf += (long long)slice * sliceC;
    if (EPI == 2) Cb += (long long)slice * sliceC;

    // staging geometry: lane -> row (lane>>3), phys k-slot (lane&7);
    // source k-slot pre-swizzled so reads XOR by (row&7).
    const int lr  = lane >> 3;
    const int skE = (((lane & 7) ^ (lr & 7)) << 3);
    const ushort_t* Bsrc = Bt + (size_t)(colBase + wave * 32 + lr) * ldb + skE;
    const ushort_t* Asrc = A + (size_t)(rowBase + wave * 32 + lr) * lda + skE;

    auto stageA = [&](int t) {
        ushort_t* d = &As[t & 1][wave * 32 * 64];
        if (AMODE == 0) {
            const ushort_t* s = Asrc + (size_t)(kbase + t) * 64;
            #pragma unroll
            for (int j = 0; j < 4; ++j)
                gload16(s + (size_t)(j * 8) * lda, d + j * 512);
        } else {
            int seg  = t >> 3;                                   // 8 k-tiles per 512-segment
            int dts  = (seg == 0) ? 0 : (seg == 1 ? (T_SEQ - 1) : 1);
            int colE = ((t & 7) << 6) + skE;
            #pragma unroll
            for (int j = 0; j < 4; ++j) {
                int gr = rowBase + wave * 32 + j * 8 + lr;
                int sr = (gr & ~(T_SEQ - 1)) | ((gr + dts) & (T_SEQ - 1));
                gload16(A + (size_t)sr * DM + colE, d + j * 512);
            }
        }
    };
    auto stageB = [&](int t) {
        ushort_t* d = &Bs[t & 1][wave * 32 * 64];
        const ushort_t* s = Bsrc + (size_t)(kbase + t) * 64;
        #pragma unroll
        for (int j = 0; j < 4; ++j)
            gload16(s + (size_t)(j * 8) * ldb, d + j * 512);
    };

    // MFMA fragment read geometry (16x16x32)
    const int l15 = lane & 15;
    const int sl0 = (((lane >> 4) ^ (lane & 7))) << 3;       // kstep0 slot offset (elems)
    const int sl1 = (((lane >> 4) + 4) ^ (lane & 7)) << 3;   // kstep1
    const int aoff = (wm * 64 + l15) * 64;
    const int boff = (wn * 64 + l15) * 64;

    f32x4 acc[4][4] = {};
    bf16x8 Ar[2][4], Br[2][4];   // [kstep][frag]

    // prologue: tiles 0 and 1 fully staged; wait tile0 (leave tile1's 8 in flight)
    stageA(0); stageB(0);
    if (ktiles > 1) { stageA(1); stageB(1); VMCNT8(); } else { VMCNT0(); }
    BAR();

    for (int t = 0; t < ktiles; ++t) {
        const int cur = t & 1;
        // read all 16 frags of buf[cur]
        #pragma unroll
        for (int m = 0; m < 4; ++m) {
            int base = aoff + m * 1024;
            Ar[0][m] = *(const bf16x8*)&As[cur][base + sl0];
            Ar[1][m] = *(const bf16x8*)&As[cur][base + sl1];
        }
        #pragma unroll
        for (int n = 0; n < 4; ++n) {
            int base = boff + n * 1024;
            Br[0][n] = *(const bf16x8*)&Bs[cur][base + sl0];
            Br[1][n] = *(const bf16x8*)&Bs[cur][base + sl1];
        }
        LGKM0();
        BAR();                               // all waves' reads of buf[cur] retired
        const bool pre = (t + 2 < ktiles);
        if (pre) { stageA(t + 2); stageB(t + 2); }   // overwrite buf[cur]
        __builtin_amdgcn_s_setprio(1);
        #pragma unroll
        for (int k = 0; k < 2; ++k)
            #pragma unroll
            for (int m = 0; m < 4; ++m)
                #pragma unroll
                for (int n = 0; n < 4; ++n)
                    acc[m][n] = __builtin_amdgcn_mfma_f32_16x16x32_bf16(
                        Ar[k][m], Br[k][n], acc[m][n], 0, 0, 0);
        __builtin_amdgcn_s_setprio(0);
        if (pre) { VMCNT8(); } else { VMCNT0(); }    // tile t+1 fully landed
        BAR();
    }

    // epilogue
    const int cl = l15, rl = (lane >> 4) << 2;
    if constexpr (EPI == 0) {
        #pragma unroll
        for (int mf = 0; mf < 4; ++mf) {
            int gr = rowBase + wm * 64 + mf * 16 + rl;
            #pragma unroll
            for (int nf = 0; nf < 4; ++nf) {
                int gc = colBase + wn * 64 + nf * 16 + cl;
                #pragma unroll
                for (int i = 0; i < 4; ++i)
                    Cf[(size_t)(gr + i) * ldc + gc] = acc[mf][nf][i];
            }
        }
    } else if constexpr (EPI == 2) {
        #pragma unroll
        for (int mf = 0; mf < 4; ++mf) {
            int gr = rowBase + wm * 64 + mf * 16 + rl;
            #pragma unroll
            for (int nf = 0; nf < 4; ++nf) {
                int gc = colBase + wn * 64 + nf * 16 + cl;
                #pragma unroll
                for (int i = 0; i < 4; ++i)
                    Cb[(size_t)(gr + i) * ldc + gc] = f2bf(acc[mf][nf][i]);
            }
        }
    } else {
        int r = (colBase + wn * 64) >> 10;   // 64-col span never crosses a rule boundary
        float bv[4];
        #pragma unroll
        for (int nf = 0; nf < 4; ++nf)
            bv[nf] = bias[r * H2 + ((colBase + wn * 64 + nf * 16 + cl) & (H2 - 1))];
        #pragma unroll
        for (int mf = 0; mf < 4; ++mf) {
            int gr = rowBase + wm * 64 + mf * 16 + rl;
            #pragma unroll
            for (int i = 0; i < 4; ++i) {
                float rwv = rwp[((gr + i) & (T_SEQ - 1)) * NR + r];
                #pragma unroll
                for (int nf = 0; nf < 4; ++nf) {
                    int gc = colBase + wn * 64 + nf * 16 + cl;
                    float v = acc[mf][nf][i] + bv[nf];
                    v = gelu_fast(v) * rwv;
                    Cb[(size_t)(gr + i) * ldc + gc] = f2bf(v);
                }
            }
        }
    }
}

extern "C" void kernel_launch(void* const* d_in, const int* in_sizes, int n_in,
                              void* d_out, int out_size, void* d_ws, size_t ws_size,
                              hipStream_t stream)
{
    const int*   tokens = (const int*)d_in[0];
    const float* gate   = (const float*)d_in[1];
    const float* emb    = (const float*)d_in[2];
    const float* pos    = (const float*)d_in[3];
    const float* w1     = (const float*)d_in[4];
    const float* b1     = (const float*)d_in[5];
    const float* w2     = (const float*)d_in[6];
    const float* b2     = (const float*)d_in[7];
    const float* selw   = (const float*)d_in[8];
    const float* selb   = (const float*)d_in[9];
    const float* ng     = (const float*)d_in[10];
    const float* nbm    = (const float*)d_in[11];
    const float* lnfg   = (const float*)d_in[12];
    const float* lnfb   = (const float*)d_in[13];
    const float* headw  = (const float*)d_in[14];
    float* out = (float*)d_out;
    (void)in_sizes; (void)n_in; (void)out_size; (void)ws_size;

    size_t off = 0;
    auto alloc = [&](size_t bytes) {
        void* p = (char*)d_ws + off;
        off += (bytes + 255) & ~(size_t)255;
        return p;
    };
    float*    x    = (float*)alloc((size_t)BT * DM * 4);
    ushort_t* xbf  = (ushort_t*)alloc((size_t)BT * DM * 2);
    ushort_t* evp  = (ushort_t*)alloc((size_t)2 * BT * DM * 2);
    ushort_t* W1t  = (ushort_t*)alloc((size_t)NR * H2 * K1 * 2);
    ushort_t* W2t  = (ushort_t*)alloc((size_t)DM * HN * 2);
    ushort_t* HWt  = (ushort_t*)alloc((size_t)VSZ * DM * 2);
    float*    rw   = (float*)alloc((size_t)T_SEQ * NR * 4);
    float*    b2rw = (float*)alloc((size_t)T_SEQ * DM * 4);
    ushort_t* H    = (ushort_t*)alloc((size_t)BT * HN * 2);

    // --- weight conversion / transpose ---
    transpose_f32_bf16<<<dim3(H2 / 32, K1 / 32, NR), dim3(32, 8), 0, stream>>>(
        w1, W1t, K1, H2, (long long)K1 * H2, (long long)H2 * K1, K1);
    transpose_f32_bf16<<<dim3(DM / 32, H2 / 32, NR), dim3(32, 8), 0, stream>>>(
        w2, W2t, H2, DM, (long long)H2 * DM, (long long)H2, HN);
    transpose_f32_bf16<<<dim3(VSZ / 32, DM / 32, 1), dim3(32, 8), 0, stream>>>(
        headw, HWt, DM, VSZ, 0LL, 0LL, DM);

    // --- x = embed + pos (f32 + bf16); rule weights + b2rw table ---
    embed_pos<<<dim3(BT), dim3(256), 0, stream>>>(tokens, emb, pos, x, xbf);
    rw_kernel<<<dim3(T_SEQ), dim3(64), 0, stream>>>(gate, selw, selb, b2, rw, b2rw);

    // --- 5 CA steps ---
    for (int s = 0; s < NSTEP; ++s) {
        // GEMM1: H = bf16(gelu(NB @ W1 + b1) * rw); 64x64 tiles, tm-fastest
        gemm128<1, 1><<<dim3(4096), dim3(256), 0, stream>>>(
            xbf, W1t, nullptr, H, /*nTmG*/64, /*gridTn*/64,
            /*nPerSlice*/4096, /*ktiles*/K1 / 64,
            DM, K1, HN, 0LL, b1, rw);
        // GEMM2: evp[slice] = bf16(H @ W2), split-K x2; 64x4 tiles
        gemm128<2, 0><<<dim3(512), dim3(256), 0, stream>>>(
            H, W2t, nullptr, evp, /*nTmG*/64, /*gridTn*/4,
            /*nPerSlice*/256, /*ktiles*/HN / 64 / 2,
            HN, HN, DM, (long long)BT * DM, nullptr, nullptr);
        if (s < NSTEP - 1) {
            ln_kernel<0><<<dim3(BT / 4), dim3(256), 0, stream>>>(
                x, evp, b2rw, ng + s * DM, nbm + s * DM, nullptr, nullptr, x, xbf);
        } else {
            // fused: step-5 LN + final LN -> xbf (x5 never materialized)
            ln_kernel<2><<<dim3(BT / 4), dim3(256), 0, stream>>>(
                x, evp, b2rw, ng + s * DM, nbm + s * DM, lnfg, lnfb, nullptr, xbf);
        }
    }

    // --- head GEMM -> f32 out; 64x250 tiles ---
    gemm128<0, 0><<<dim3(16000), dim3(256), 0, stream>>>(
        xbf, HWt, out, nullptr, /*nTmG*/64, /*gridTn*/250,
        /*nPerSlice*/16000, /*ktiles*/DM / 64,
        DM, DM, VSZ, 0LL, nullptr, nullptr);
}

// Round 9
// 2076.878 us; speedup vs baseline: 1.1440x; 1.1440x over previous
//
#include <hip/hip_runtime.h>

#define T_SEQ 2048
#define BT    8192
#define DM    512
#define NR    8
#define NSTEP 5
#define K1    1536   // 3*D
#define H2    1024   // 2*D
#define VSZ   32000
#define HN    8192   // NR*H2

using ushort_t = unsigned short;
using bf16x8 = __attribute__((ext_vector_type(8))) __bf16;
using f32x4  = __attribute__((ext_vector_type(4))) float;

__device__ __forceinline__ ushort_t f2bf(float f) {
    union { float f; unsigned u; } v; v.f = f;
    unsigned r = v.u + 0x7FFFu + ((v.u >> 16) & 1u);
    return (ushort_t)(r >> 16);
}

__device__ __forceinline__ float bf2f(unsigned hi) {
    union { unsigned u; float f; } v; v.u = hi << 16;
    return v.f;
}

__device__ __forceinline__ void gload16(const void* g, void* l) {
    __builtin_amdgcn_global_load_lds((const __attribute__((address_space(1))) void*)g,
                                     (__attribute__((address_space(3))) void*)l, 16, 0, 0);
}

// gelu(tanh form) = x * sigmoid(x*(2.3022861 + 0.10294456*x^2))  [exact identity]
__device__ __forceinline__ float gelu_fast(float x) {
    float x2 = x * x;
    float u  = x * fmaf(x2, 0.10294456f, 2.3022861f);   // 2y*log2(e)
    float e  = exp2f(-u);
    return x * __builtin_amdgcn_rcpf(1.0f + e);
}

#define BAR()    __builtin_amdgcn_s_barrier()
#define VMCNT8() asm volatile("s_waitcnt vmcnt(8)" ::: "memory")
#define VMCNT0() asm volatile("s_waitcnt vmcnt(0)" ::: "memory")

// transpose f32 src[z][K][N] -> bf16 dst[z*dstBatch + n*dstRow + k]
__global__ void transpose_f32_bf16(const float* __restrict__ src, ushort_t* __restrict__ dst,
                                   int K, int N, long long srcBatch, long long dstBatch, int dstRow)
{
    __shared__ float tile[32][33];
    src += (size_t)blockIdx.z * srcBatch;
    dst += (size_t)blockIdx.z * dstBatch;
    int n0 = blockIdx.x * 32, k0 = blockIdx.y * 32;
    int tx = threadIdx.x, ty = threadIdx.y;
    #pragma unroll
    for (int i = 0; i < 32; i += 8)
        tile[ty + i][tx] = src[(size_t)(k0 + ty + i) * N + (n0 + tx)];
    __syncthreads();
    #pragma unroll
    for (int i = 0; i < 32; i += 8)
        dst[(size_t)(n0 + ty + i) * dstRow + (k0 + tx)] = f2bf(tile[tx][ty + i]);
}

__global__ void embed_pos(const int* __restrict__ tokens, const float* __restrict__ emb,
                          const float* __restrict__ pos, float* __restrict__ x,
                          ushort_t* __restrict__ xbf)
{
    int row = blockIdx.x;
    int t = row & (T_SEQ - 1);
    int tok = tokens[row];
    int i = threadIdx.x;              // 256 threads * float2 = 512 floats
    float2 e = ((const float2*)(emb + (size_t)tok * DM))[i];
    float2 p = ((const float2*)(pos + (size_t)t * DM))[i];
    float2 v = make_float2(e.x + p.x, e.y + p.y);
    ((float2*)(x + (size_t)row * DM))[i] = v;
    ushort_t bb[2] = { f2bf(v.x), f2bf(v.y) };
    ((unsigned*)(xbf + (size_t)row * DM))[i] = *(const unsigned*)bb;
}

// rw[t,r] softmax + b2rw[t,d] = sum_r rw[t,r]*b2[r,d]   (step-invariant)
__global__ void rw_kernel(const float* __restrict__ gate, const float* __restrict__ selw,
                          const float* __restrict__ selb, const float* __restrict__ b2,
                          float* __restrict__ rw, float* __restrict__ b2rw)
{
    int t = blockIdx.x, lane = threadIdx.x;  // 64 lanes
    float p[NR];
    #pragma unroll
    for (int r = 0; r < NR; ++r) p[r] = 0.f;
    for (int d = lane; d < DM; d += 64) {
        float gv = gate[(size_t)t * DM + d] * 0.001f;
        const float* swr = selw + (size_t)d * NR;
        #pragma unroll
        for (int r = 0; r < NR; ++r) p[r] += gv * swr[r];
    }
    #pragma unroll
    for (int o = 32; o; o >>= 1) {
        #pragma unroll
        for (int r = 0; r < NR; ++r) p[r] += __shfl_xor(p[r], o, 64);
    }
    float mx = -1e30f;
    #pragma unroll
    for (int r = 0; r < NR; ++r) { p[r] += selb[r]; mx = fmaxf(mx, p[r]); }
    float s = 0.f;
    #pragma unroll
    for (int r = 0; r < NR; ++r) { p[r] = expf(p[r] - mx); s += p[r]; }
    float inv = 1.0f / s;
    #pragma unroll
    for (int r = 0; r < NR; ++r) p[r] *= inv;
    if (lane < NR) rw[t * NR + lane] = p[lane];
    #pragma unroll
    for (int it = 0; it < DM / 64; ++it) {
        int d = it * 64 + lane;
        float a = 0.f;
        #pragma unroll
        for (int r = 0; r < NR; ++r) a += p[r] * b2[r * DM + d];
        b2rw[(size_t)t * DM + d] = a;
    }
}

// Row-per-wave LN, 4 evp slices. MODE 0: x = LN(x + evp + b2rw)*g + b -> x f32 + xbf.
// MODE 2: v = LN(x + evp + b2rw)*g + b; xbf = bf16(LN(v)*fg + fb)  (fused final)
template<int MODE>
__global__ __launch_bounds__(256)
void ln_kernel(const float* __restrict__ xin, const ushort_t* __restrict__ evp,
               const float* __restrict__ b2rw,
               const float* __restrict__ g, const float* __restrict__ b,
               const float* __restrict__ fg, const float* __restrict__ fb,
               float* __restrict__ xout, ushort_t* __restrict__ xbf)
{
    int row = (blockIdx.x << 2) + (threadIdx.x >> 6);
    int lane = threadIdx.x & 63;
    int t = row & (T_SEQ - 1);
    int d0 = lane << 3;

    float s[8];
    {
        float4 a = *(const float4*)(xin + (size_t)row * DM + d0);
        float4 c = *(const float4*)(xin + (size_t)row * DM + d0 + 4);
        s[0]=a.x; s[1]=a.y; s[2]=a.z; s[3]=a.w; s[4]=c.x; s[5]=c.y; s[6]=c.z; s[7]=c.w;
    }
    #pragma unroll
    for (int sl = 0; sl < 4; ++sl) {
        uint4 u = *(const uint4*)(evp + ((size_t)sl * BT + row) * DM + d0);
        const unsigned w[4] = { u.x, u.y, u.z, u.w };
        #pragma unroll
        for (int j = 0; j < 4; ++j) {
            s[2*j]   += bf2f(w[j] & 0xffffu);
            s[2*j+1] += bf2f(w[j] >> 16);
        }
    }
    {
        float4 a = *(const float4*)(b2rw + (size_t)t * DM + d0);
        float4 c = *(const float4*)(b2rw + (size_t)t * DM + d0 + 4);
        s[0]+=a.x; s[1]+=a.y; s[2]+=a.z; s[3]+=a.w; s[4]+=c.x; s[5]+=c.y; s[6]+=c.z; s[7]+=c.w;
    }
    float sum = 0.f, sq = 0.f;
    #pragma unroll
    for (int j = 0; j < 8; ++j) { sum += s[j]; sq += s[j] * s[j]; }
    #pragma unroll
    for (int o = 32; o; o >>= 1) { sum += __shfl_xor(sum, o, 64); sq += __shfl_xor(sq, o, 64); }
    float mean = sum * (1.0f / DM);
    float var  = sq * (1.0f / DM) - mean * mean;
    float rstd = rsqrtf(var + 1e-5f);

    float o8[8];
    #pragma unroll
    for (int j = 0; j < 8; ++j)
        o8[j] = (s[j] - mean) * rstd * g[d0 + j] + b[d0 + j];

    if constexpr (MODE == 0) {
        float4 w0 = make_float4(o8[0], o8[1], o8[2], o8[3]);
        float4 w1 = make_float4(o8[4], o8[5], o8[6], o8[7]);
        *(float4*)(xout + (size_t)row * DM + d0) = w0;
        *(float4*)(xout + (size_t)row * DM + d0 + 4) = w1;
        ushort_t bb[8];
        #pragma unroll
        for (int j = 0; j < 8; ++j) bb[j] = f2bf(o8[j]);
        *(uint4*)(xbf + (size_t)row * DM + d0) = *(const uint4*)bb;
    } else {
        float sum2 = 0.f, sq2 = 0.f;
        #pragma unroll
        for (int j = 0; j < 8; ++j) { sum2 += o8[j]; sq2 += o8[j] * o8[j]; }
        #pragma unroll
        for (int o = 32; o; o >>= 1) { sum2 += __shfl_xor(sum2, o, 64); sq2 += __shfl_xor(sq2, o, 64); }
        float m2 = sum2 * (1.0f / DM);
        float v2 = sq2 * (1.0f / DM) - m2 * m2;
        float r2 = rsqrtf(v2 + 1e-5f);
        ushort_t bb[8];
        #pragma unroll
        for (int j = 0; j < 8; ++j)
            bb[j] = f2bf((o8[j] - m2) * r2 * fg[d0 + j] + fb[d0 + j]);
        *(uint4*)(xbf + (size_t)row * DM + d0) = *(const uint4*)bb;
    }
}

// ---------------------------------------------------------------------------
// 256x256 bf16 GEMM, 16x16x32 MFMA, BK=64, 8 waves. 3-phase K-tile (R7) with
// DEEP B PREFETCH: A double-buffered (64 KB), B TRIPLE-buffered (96 KB),
// LDS = 160 KB (full CU). B staged 2 tiles ahead (covers L3/HBM latency).
//   P1: read ALL A frags + B(nh0) | stage B(t+2) -> Bs[(t+2)%3]
//   P2: read B(nh1)               | stage A(t+2) -> As[t&1] (reads retired in P1)
//   P3: pure 32-MFMA cluster, counted vmcnt(8) (tail: vmcnt(0)), BAR
// Ledger: prologue stages A0,B0,A1,B1 (16), vmcnt(8) -> A0,B0 landed.
// Tile t issues B(t+2),A(t+2) (+8 -> 16 outstanding); vmcnt(8) waits exactly
// A(t+1),B(t+1) (oldest 8). Tail (t+2>=kt): vmcnt(0) drains the rest.
// Buffer safety: B(t+2)%3 != B(t)%3 (read) and != B(t+1)%3 (landed, read next).
// A staging safety identical to R7 (proven).
// C[M,N] = A[M,K] @ Bt[N,K]^T.  AMODE 1: A = xbf[BT][512], K=1536 via row roll.
// Grid: XCD-bijective swizzle -> slice -> 2D groups (nTmG x nTnG, tn-fastest).
// EPI 0: Cf[slice]=acc f32.  EPI 1: Cb=bf16(gelu(acc+b1)*rw).  EPI 2: Cb[slice]=bf16(acc).
// ---------------------------------------------------------------------------
template<int EPI, int AMODE>
__global__ __launch_bounds__(512, 2)
void gemm8(const ushort_t* __restrict__ A, const ushort_t* __restrict__ Bt,
           float* __restrict__ Cf, ushort_t* __restrict__ Cb,
           int nTmG, int nTnG, int gridTn, int nPerSlice, int ktiles, int nTnTot,
           int lda, int ldb, int ldc, long long sliceC,
           const float* __restrict__ bias, const float* __restrict__ rwp)
{
    __shared__ ushort_t As[2][256 * 64];
    __shared__ ushort_t Bs[3][256 * 64];

    const int tid  = threadIdx.x;
    const int wave = tid >> 6, lane = tid & 63;
    const int wm = wave >> 2, wn = wave & 3;

    // bijective XCD swizzle (m204)
    int nwg = gridDim.x, bid = blockIdx.x;
    int qq = nwg >> 3, rr = nwg & 7, xc = bid & 7, wi = bid >> 3;
    int wgid = (xc < rr ? xc * (qq + 1) : rr * (qq + 1) + (xc - rr) * qq) + wi;
    int slice = wgid / nPerSlice, rem = wgid - slice * nPerSlice;
    int gsz = nTmG * nTnG;
    int g = rem / gsz, li = rem - g * gsz;
    int gTn = g % gridTn, gTm = g / gridTn;
    int tm = gTm * nTmG + li / nTnG;
    int tn = gTn * nTnG + li % nTnG;
    if (tn >= nTnTot) return;          // uniform early-exit, before any barrier

    const int rowBase = tm * 256, colBase = tn * 256;
    const int kbase = slice * ktiles;
    if (EPI == 0) Cf += (long long)slice * sliceC;
    if (EPI == 2) Cb += (long long)slice * sliceC;

    // staging geometry: lane -> row (lane>>3), phys k-slot (lane&7);
    // source k-slot pre-swizzled so reads XOR by (row&7).
    const int lr  = lane >> 3;
    const int skE = (((lane & 7) ^ (lr & 7)) << 3);
    const ushort_t* Bsrc = Bt + (size_t)(colBase + wave * 32 + lr) * ldb + skE;
    const ushort_t* Asrc = A + (size_t)(rowBase + wave * 32 + lr) * lda + skE;

    auto stageA = [&](int t) {
        ushort_t* d = &As[t & 1][wave * 32 * 64];
        if (AMODE == 0) {
            const ushort_t* s = Asrc + (size_t)(kbase + t) * 64;
            #pragma unroll
            for (int j = 0; j < 4; ++j)
                gload16(s + (size_t)(j * 8) * lda, d + j * 512);
        } else {
            int seg  = t >> 3;                                   // 8 k-tiles per 512-segment
            int dts  = (seg == 0) ? 0 : (seg == 1 ? (T_SEQ - 1) : 1);
            int colE = ((t & 7) << 6) + skE;
            #pragma unroll
            for (int j = 0; j < 4; ++j) {
                int gr = rowBase + wave * 32 + j * 8 + lr;
                int sr = (gr & ~(T_SEQ - 1)) | ((gr + dts) & (T_SEQ - 1));
                gload16(A + (size_t)sr * DM + colE, d + j * 512);
            }
        }
    };
    auto stageB = [&](int t) {
        ushort_t* d = &Bs[t % 3][wave * 32 * 64];
        const ushort_t* s = Bsrc + (size_t)(kbase + t) * 64;
        #pragma unroll
        for (int j = 0; j < 4; ++j)
            gload16(s + (size_t)(j * 8) * ldb, d + j * 512);
    };

    // MFMA fragment read geometry
    const int l15 = lane & 15;
    const int sl0 = (((lane >> 4) ^ (lane & 7))) << 3;       // kstep0 slot offset (elems)
    const int sl1 = (((lane >> 4) + 4) ^ (lane & 7)) << 3;   // kstep1
    const int aoff = (wm * 128 + l15) * 64;
    const int boff = (wn * 64 + l15) * 64;

    f32x4 acc[8][4] = {};
    bf16x8 Ar[2][2][4];     // [mh][kstep][m] — full tile's A frags
    bf16x8 Br[2][2][2];     // [nh][kstep][n]

    auto readAall = [&](int buf) {
        #pragma unroll
        for (int mh = 0; mh < 2; ++mh)
            #pragma unroll
            for (int m = 0; m < 4; ++m) {
                int base = aoff + mh * 4096 + m * 1024;
                Ar[mh][0][m] = *(const bf16x8*)&As[buf][base + sl0];
                Ar[mh][1][m] = *(const bf16x8*)&As[buf][base + sl1];
            }
    };
    auto readB = [&](int buf3, int nh) {
        #pragma unroll
        for (int n = 0; n < 2; ++n) {
            int base = boff + nh * 2048 + n * 1024;
            Br[nh][0][n] = *(const bf16x8*)&Bs[buf3][base + sl0];
            Br[nh][1][n] = *(const bf16x8*)&Bs[buf3][base + sl1];
        }
    };
    auto mmaQ = [&](int mh, int nh) {
        #pragma unroll
        for (int k = 0; k < 2; ++k)
            #pragma unroll
            for (int m = 0; m < 4; ++m)
                #pragma unroll
                for (int n = 0; n < 2; ++n)
                    acc[mh * 4 + m][nh * 2 + n] = __builtin_amdgcn_mfma_f32_16x16x32_bf16(
                        Ar[mh][k][m], Br[nh][k][n], acc[mh * 4 + m][nh * 2 + n], 0, 0, 0);
    };

    // prologue: A0,B0 + A1,B1 in flight; wait A0,B0 (oldest 8)
    stageA(0); stageB(0);
    if (ktiles > 1) { stageA(1); stageB(1); VMCNT8(); } else { VMCNT0(); }
    BAR();

    for (int t = 0; t < ktiles; ++t) {
        const int curA = t & 1;
        const int curB = t % 3;
        const bool pre = (t + 2 < ktiles);
        // P1: all A frags + B(nh0); deep-prefetch B(t+2) -> Bs[(t+2)%3]
        readAall(curA); readB(curB, 0);
        if (pre) stageB(t + 2);
        BAR();
        __builtin_amdgcn_s_setprio(1); mmaQ(0, 0); __builtin_amdgcn_s_setprio(0);
        BAR();
        // P2: B(nh1); prefetch A(t+2) -> As[curA] (all As[curA] reads retired in P1)
        readB(curB, 1);
        if (pre) stageA(t + 2);
        BAR();
        __builtin_amdgcn_s_setprio(1); mmaQ(0, 1); __builtin_amdgcn_s_setprio(0);
        BAR();
        // P3: pure MFMA cluster; counted vmcnt (waits A(t+1),B(t+1) exactly)
        __builtin_amdgcn_s_setprio(1); mmaQ(1, 1); mmaQ(1, 0); __builtin_amdgcn_s_setprio(0);
        if (pre) { VMCNT8(); } else { VMCNT0(); }
        BAR();
    }

    // epilogue
    const int cl = l15, rl = (lane >> 4) << 2;
    if constexpr (EPI == 0) {
        #pragma unroll
        for (int mf = 0; mf < 8; ++mf) {
            int gr = rowBase + wm * 128 + mf * 16 + rl;
            #pragma unroll
            for (int nf = 0; nf < 4; ++nf) {
                int gc = colBase + wn * 64 + nf * 16 + cl;
                #pragma unroll
                for (int i = 0; i < 4; ++i)
                    Cf[(size_t)(gr + i) * ldc + gc] = acc[mf][nf][i];
            }
        }
    } else if constexpr (EPI == 2) {
        #pragma unroll
        for (int mf = 0; mf < 8; ++mf) {
            int gr = rowBase + wm * 128 + mf * 16 + rl;
            #pragma unroll
            for (int nf = 0; nf < 4; ++nf) {
                int gc = colBase + wn * 64 + nf * 16 + cl;
                #pragma unroll
                for (int i = 0; i < 4; ++i)
                    Cb[(size_t)(gr + i) * ldc + gc] = f2bf(acc[mf][nf][i]);
            }
        }
    } else {
        int r = (colBase + wn * 64) >> 10;   // 64-col span never crosses a rule boundary
        float bv[4];
        #pragma unroll
        for (int nf = 0; nf < 4; ++nf)
            bv[nf] = bias[r * H2 + ((colBase + wn * 64 + nf * 16 + cl) & (H2 - 1))];
        #pragma unroll
        for (int mf = 0; mf < 8; ++mf) {
            int gr = rowBase + wm * 128 + mf * 16 + rl;
            #pragma unroll
            for (int i = 0; i < 4; ++i) {
                float rwv = rwp[((gr + i) & (T_SEQ - 1)) * NR + r];
                #pragma unroll
                for (int nf = 0; nf < 4; ++nf) {
                    int gc = colBase + wn * 64 + nf * 16 + cl;
                    float v = acc[mf][nf][i] + bv[nf];
                    v = gelu_fast(v) * rwv;
                    Cb[(size_t)(gr + i) * ldc + gc] = f2bf(v);
                }
            }
        }
    }
}

extern "C" void kernel_launch(void* const* d_in, const int* in_sizes, int n_in,
                              void* d_out, int out_size, void* d_ws, size_t ws_size,
                              hipStream_t stream)
{
    const int*   tokens = (const int*)d_in[0];
    const float* gate   = (const float*)d_in[1];
    const float* emb    = (const float*)d_in[2];
    const float* pos    = (const float*)d_in[3];
    const float* w1     = (const float*)d_in[4];
    const float* b1     = (const float*)d_in[5];
    const float* w2     = (const float*)d_in[6];
    const float* b2     = (const float*)d_in[7];
    const float* selw   = (const float*)d_in[8];
    const float* selb   = (const float*)d_in[9];
    const float* ng     = (const float*)d_in[10];
    const float* nbm    = (const float*)d_in[11];
    const float* lnfg   = (const float*)d_in[12];
    const float* lnfb   = (const float*)d_in[13];
    const float* headw  = (const float*)d_in[14];
    float* out = (float*)d_out;
    (void)in_sizes; (void)n_in; (void)out_size; (void)ws_size;

    size_t off = 0;
    auto alloc = [&](size_t bytes) {
        void* p = (char*)d_ws + off;
        off += (bytes + 255) & ~(size_t)255;
        return p;
    };
    float*    x    = (float*)alloc((size_t)BT * DM * 4);
    ushort_t* xbf  = (ushort_t*)alloc((size_t)BT * DM * 2);
    ushort_t* evp  = (ushort_t*)alloc((size_t)4 * BT * DM * 2);
    ushort_t* W1t  = (ushort_t*)alloc((size_t)NR * H2 * K1 * 2);
    ushort_t* W2t  = (ushort_t*)alloc((size_t)DM * HN * 2);
    ushort_t* HWt  = (ushort_t*)alloc((size_t)VSZ * DM * 2);
    float*    rw   = (float*)alloc((size_t)T_SEQ * NR * 4);
    float*    b2rw = (float*)alloc((size_t)T_SEQ * DM * 4);
    ushort_t* H    = (ushort_t*)alloc((size_t)BT * HN * 2);

    // --- weight conversion / transpose ---
    transpose_f32_bf16<<<dim3(H2 / 32, K1 / 32, NR), dim3(32, 8), 0, stream>>>(
        w1, W1t, K1, H2, (long long)K1 * H2, (long long)H2 * K1, K1);
    transpose_f32_bf16<<<dim3(DM / 32, H2 / 32, NR), dim3(32, 8), 0, stream>>>(
        w2, W2t, H2, DM, (long long)H2 * DM, (long long)H2, HN);
    transpose_f32_bf16<<<dim3(VSZ / 32, DM / 32, 1), dim3(32, 8), 0, stream>>>(
        headw, HWt, DM, VSZ, 0LL, 0LL, DM);

    // --- x = embed + pos (f32 + bf16); rule weights + b2rw table ---
    embed_pos<<<dim3(BT), dim3(256), 0, stream>>>(tokens, emb, pos, x, xbf);
    rw_kernel<<<dim3(T_SEQ), dim3(64), 0, stream>>>(gate, selw, selb, b2, rw, b2rw);

    // --- 5 CA steps ---
    for (int s = 0; s < NSTEP; ++s) {
        // GEMM1: H = bf16(gelu(NB @ W1 + b1) * rw); groups: tn-shared per XCD (32x1)
        gemm8<1, 1><<<dim3(1024), dim3(512), 0, stream>>>(
            xbf, W1t, nullptr, H, /*nTmG*/32, /*nTnG*/1, /*gridTn*/32,
            /*nPerSlice*/1024, /*ktiles*/K1 / 64, /*nTnTot*/32,
            DM, K1, HN, 0LL, b1, rw);
        // GEMM2: evp[slice] = bf16(H @ W2) (split-K x4); 32x2 group
        gemm8<2, 0><<<dim3(256), dim3(512), 0, stream>>>(
            H, W2t, nullptr, evp, /*nTmG*/32, /*nTnG*/2, /*gridTn*/1,
            /*nPerSlice*/64, /*ktiles*/HN / 64 / 4, /*nTnTot*/2,
            HN, HN, DM, (long long)BT * DM, nullptr, nullptr);
        if (s < NSTEP - 1) {
            ln_kernel<0><<<dim3(BT / 4), dim3(256), 0, stream>>>(
                x, evp, b2rw, ng + s * DM, nbm + s * DM, nullptr, nullptr, x, xbf);
        } else {
            // fused: step-5 LN + final LN -> xbf (x5 never materialized)
            ln_kernel<2><<<dim3(BT / 4), dim3(256), 0, stream>>>(
                x, evp, b2rw, ng + s * DM, nbm + s * DM, lnfg, lnfb, nullptr, xbf);
        }
    }

    // --- head GEMM -> f32 out; 8x4 groups (A 2MB + B 1MB per XCD round, L2-fit) ---
    gemm8<0, 0><<<dim3(4096), dim3(512), 0, stream>>>(
        xbf, HWt, out, nullptr, /*nTmG*/8, /*nTnG*/4, /*gridTn*/32,
        /*nPerSlice*/4096, /*ktiles*/DM / 64, /*nTnTot*/125,
        DM, DM, VSZ, 0LL, nullptr, nullptr);
}

// Round 10
// 2072.610 us; speedup vs baseline: 1.1463x; 1.0021x over previous
//
#include <hip/hip_runtime.h>

#define T_SEQ 2048
#define BT    8192
#define DM    512
#define NR    8
#define NSTEP 5
#define K1    1536   // 3*D
#define H2    1024   // 2*D
#define VSZ   32000
#define HN    8192   // NR*H2

using ushort_t = unsigned short;
using bf16x8 = __attribute__((ext_vector_type(8))) __bf16;
using f32x4  = __attribute__((ext_vector_type(4))) float;

__device__ __forceinline__ ushort_t f2bf(float f) {
    union { float f; unsigned u; } v; v.f = f;
    unsigned r = v.u + 0x7FFFu + ((v.u >> 16) & 1u);
    return (ushort_t)(r >> 16);
}

__device__ __forceinline__ float bf2f(unsigned hi) {
    union { unsigned u; float f; } v; v.u = hi << 16;
    return v.f;
}

__device__ __forceinline__ void gload16(const void* g, void* l) {
    __builtin_amdgcn_global_load_lds((const __attribute__((address_space(1))) void*)g,
                                     (__attribute__((address_space(3))) void*)l, 16, 0, 0);
}

// gelu(tanh form) = x * sigmoid(x*(2.3022861 + 0.10294456*x^2))  [exact identity]
__device__ __forceinline__ float gelu_fast(float x) {
    float x2 = x * x;
    float u  = x * fmaf(x2, 0.10294456f, 2.3022861f);   // 2y*log2(e)
    float e  = exp2f(-u);
    return x * __builtin_amdgcn_rcpf(1.0f + e);
}

#define BAR()    __builtin_amdgcn_s_barrier()
#define VMCNT8() asm volatile("s_waitcnt vmcnt(8)" ::: "memory")
#define VMCNT0() asm volatile("s_waitcnt vmcnt(0)" ::: "memory")

// transpose f32 src[z][K][N] -> bf16 dst[z*dstBatch + n*dstRow + k]
__global__ void transpose_f32_bf16(const float* __restrict__ src, ushort_t* __restrict__ dst,
                                   int K, int N, long long srcBatch, long long dstBatch, int dstRow)
{
    __shared__ float tile[32][33];
    src += (size_t)blockIdx.z * srcBatch;
    dst += (size_t)blockIdx.z * dstBatch;
    int n0 = blockIdx.x * 32, k0 = blockIdx.y * 32;
    int tx = threadIdx.x, ty = threadIdx.y;
    #pragma unroll
    for (int i = 0; i < 32; i += 8)
        tile[ty + i][tx] = src[(size_t)(k0 + ty + i) * N + (n0 + tx)];
    __syncthreads();
    #pragma unroll
    for (int i = 0; i < 32; i += 8)
        dst[(size_t)(n0 + ty + i) * dstRow + (k0 + tx)] = f2bf(tile[tx][ty + i]);
}

__global__ void embed_pos(const int* __restrict__ tokens, const float* __restrict__ emb,
                          const float* __restrict__ pos, float* __restrict__ x,
                          ushort_t* __restrict__ xbf)
{
    int row = blockIdx.x;
    int t = row & (T_SEQ - 1);
    int tok = tokens[row];
    int i = threadIdx.x;              // 256 threads * float2 = 512 floats
    float2 e = ((const float2*)(emb + (size_t)tok * DM))[i];
    float2 p = ((const float2*)(pos + (size_t)t * DM))[i];
    float2 v = make_float2(e.x + p.x, e.y + p.y);
    ((float2*)(x + (size_t)row * DM))[i] = v;
    ushort_t bb[2] = { f2bf(v.x), f2bf(v.y) };
    ((unsigned*)(xbf + (size_t)row * DM))[i] = *(const unsigned*)bb;
}

// rw[t,r] softmax + b2rw[t,d] = sum_r rw[t,r]*b2[r,d]   (step-invariant)
__global__ void rw_kernel(const float* __restrict__ gate, const float* __restrict__ selw,
                          const float* __restrict__ selb, const float* __restrict__ b2,
                          float* __restrict__ rw, float* __restrict__ b2rw)
{
    int t = blockIdx.x, lane = threadIdx.x;  // 64 lanes
    float p[NR];
    #pragma unroll
    for (int r = 0; r < NR; ++r) p[r] = 0.f;
    for (int d = lane; d < DM; d += 64) {
        float gv = gate[(size_t)t * DM + d] * 0.001f;
        const float* swr = selw + (size_t)d * NR;
        #pragma unroll
        for (int r = 0; r < NR; ++r) p[r] += gv * swr[r];
    }
    #pragma unroll
    for (int o = 32; o; o >>= 1) {
        #pragma unroll
        for (int r = 0; r < NR; ++r) p[r] += __shfl_xor(p[r], o, 64);
    }
    float mx = -1e30f;
    #pragma unroll
    for (int r = 0; r < NR; ++r) { p[r] += selb[r]; mx = fmaxf(mx, p[r]); }
    float s = 0.f;
    #pragma unroll
    for (int r = 0; r < NR; ++r) { p[r] = expf(p[r] - mx); s += p[r]; }
    float inv = 1.0f / s;
    #pragma unroll
    for (int r = 0; r < NR; ++r) p[r] *= inv;
    if (lane < NR) rw[t * NR + lane] = p[lane];
    #pragma unroll
    for (int it = 0; it < DM / 64; ++it) {
        int d = it * 64 + lane;
        float a = 0.f;
        #pragma unroll
        for (int r = 0; r < NR; ++r) a += p[r] * b2[r * DM + d];
        b2rw[(size_t)t * DM + d] = a;
    }
}

// Row-per-wave LN, 4 evp slices. MODE 0: x = LN(x + evp + b2rw)*g + b -> x f32 + xbf.
// MODE 2: v = LN(x + evp + b2rw)*g + b; xbf = bf16(LN(v)*fg + fb)  (fused final)
template<int MODE>
__global__ __launch_bounds__(256)
void ln_kernel(const float* __restrict__ xin, const ushort_t* __restrict__ evp,
               const float* __restrict__ b2rw,
               const float* __restrict__ g, const float* __restrict__ b,
               const float* __restrict__ fg, const float* __restrict__ fb,
               float* __restrict__ xout, ushort_t* __restrict__ xbf)
{
    int row = (blockIdx.x << 2) + (threadIdx.x >> 6);
    int lane = threadIdx.x & 63;
    int t = row & (T_SEQ - 1);
    int d0 = lane << 3;

    float s[8];
    {
        float4 a = *(const float4*)(xin + (size_t)row * DM + d0);
        float4 c = *(const float4*)(xin + (size_t)row * DM + d0 + 4);
        s[0]=a.x; s[1]=a.y; s[2]=a.z; s[3]=a.w; s[4]=c.x; s[5]=c.y; s[6]=c.z; s[7]=c.w;
    }
    #pragma unroll
    for (int sl = 0; sl < 4; ++sl) {
        uint4 u = *(const uint4*)(evp + ((size_t)sl * BT + row) * DM + d0);
        const unsigned w[4] = { u.x, u.y, u.z, u.w };
        #pragma unroll
        for (int j = 0; j < 4; ++j) {
            s[2*j]   += bf2f(w[j] & 0xffffu);
            s[2*j+1] += bf2f(w[j] >> 16);
        }
    }
    {
        float4 a = *(const float4*)(b2rw + (size_t)t * DM + d0);
        float4 c = *(const float4*)(b2rw + (size_t)t * DM + d0 + 4);
        s[0]+=a.x; s[1]+=a.y; s[2]+=a.z; s[3]+=a.w; s[4]+=c.x; s[5]+=c.y; s[6]+=c.z; s[7]+=c.w;
    }
    float sum = 0.f, sq = 0.f;
    #pragma unroll
    for (int j = 0; j < 8; ++j) { sum += s[j]; sq += s[j] * s[j]; }
    #pragma unroll
    for (int o = 32; o; o >>= 1) { sum += __shfl_xor(sum, o, 64); sq += __shfl_xor(sq, o, 64); }
    float mean = sum * (1.0f / DM);
    float var  = sq * (1.0f / DM) - mean * mean;
    float rstd = rsqrtf(var + 1e-5f);

    float o8[8];
    #pragma unroll
    for (int j = 0; j < 8; ++j)
        o8[j] = (s[j] - mean) * rstd * g[d0 + j] + b[d0 + j];

    if constexpr (MODE == 0) {
        float4 w0 = make_float4(o8[0], o8[1], o8[2], o8[3]);
        float4 w1 = make_float4(o8[4], o8[5], o8[6], o8[7]);
        *(float4*)(xout + (size_t)row * DM + d0) = w0;
        *(float4*)(xout + (size_t)row * DM + d0 + 4) = w1;
        ushort_t bb[8];
        #pragma unroll
        for (int j = 0; j < 8; ++j) bb[j] = f2bf(o8[j]);
        *(uint4*)(xbf + (size_t)row * DM + d0) = *(const uint4*)bb;
    } else {
        float sum2 = 0.f, sq2 = 0.f;
        #pragma unroll
        for (int j = 0; j < 8; ++j) { sum2 += o8[j]; sq2 += o8[j] * o8[j]; }
        #pragma unroll
        for (int o = 32; o; o >>= 1) { sum2 += __shfl_xor(sum2, o, 64); sq2 += __shfl_xor(sq2, o, 64); }
        float m2 = sum2 * (1.0f / DM);
        float v2 = sq2 * (1.0f / DM) - m2 * m2;
        float r2 = rsqrtf(v2 + 1e-5f);
        ushort_t bb[8];
        #pragma unroll
        for (int j = 0; j < 8; ++j)
            bb[j] = f2bf((o8[j] - m2) * r2 * fg[d0 + j] + fb[d0 + j]);
        *(uint4*)(xbf + (size_t)row * DM + d0) = *(const uint4*)bb;
    }
}

// ---------------------------------------------------------------------------
// 256x256 bf16 GEMM, 16x16x32 MFMA, BK=64, 8 waves. 3-phase K-tile (R7) with
// DEEP B PREFETCH: A double-buffered (64 KB), B TRIPLE-buffered (96 KB),
// LDS = 160 KB (full CU). B staged 2 tiles ahead (covers L3/HBM latency).
//   P1: read ALL A frags + B(nh0) | stage B(t+2) -> Bs[(t+2)%3]
//   P2: read B(nh1)               | stage A(t+2) -> As[t&1] (reads retired in P1)
//   P3: pure 32-MFMA cluster, counted vmcnt(8) (tail: vmcnt(0)), BAR
// Ledger: prologue stages A0,B0,A1,B1 (16), vmcnt(8) -> A0,B0 landed.
// Tile t issues B(t+2),A(t+2) (+8 -> 16 outstanding); vmcnt(8) waits exactly
// A(t+1),B(t+1) (oldest 8). Tail (t+2>=kt): vmcnt(0) drains the rest.
// Buffer safety: B(t+2)%3 != B(t)%3 (read) and != B(t+1)%3 (landed, read next).
// A staging safety identical to R7 (proven).
// C[M,N] = A[M,K] @ Bt[N,K]^T.  AMODE 1: A = xbf[BT][512], K=1536 via row roll.
// Grid: XCD-bijective swizzle -> slice -> 2D groups (nTmG x nTnG, tn-fastest).
// EPI 0: Cf[slice]=acc f32.  EPI 1: Cb=bf16(gelu(acc+b1)*rw).  EPI 2: Cb[slice]=bf16(acc).
// ---------------------------------------------------------------------------
template<int EPI, int AMODE>
__global__ __launch_bounds__(512, 2)
void gemm8(const ushort_t* __restrict__ A, const ushort_t* __restrict__ Bt,
           float* __restrict__ Cf, ushort_t* __restrict__ Cb,
           int nTmG, int nTnG, int gridTn, int nPerSlice, int ktiles, int nTnTot,
           int lda, int ldb, int ldc, long long sliceC,
           const float* __restrict__ bias, const float* __restrict__ rwp)
{
    __shared__ ushort_t As[2][256 * 64];
    __shared__ ushort_t Bs[3][256 * 64];

    const int tid  = threadIdx.x;
    const int wave = tid >> 6, lane = tid & 63;
    const int wm = wave >> 2, wn = wave & 3;

    // bijective XCD swizzle (m204)
    int nwg = gridDim.x, bid = blockIdx.x;
    int qq = nwg >> 3, rr = nwg & 7, xc = bid & 7, wi = bid >> 3;
    int wgid = (xc < rr ? xc * (qq + 1) : rr * (qq + 1) + (xc - rr) * qq) + wi;
    int slice = wgid / nPerSlice, rem = wgid - slice * nPerSlice;
    int gsz = nTmG * nTnG;
    int g = rem / gsz, li = rem - g * gsz;
    int gTn = g % gridTn, gTm = g / gridTn;
    int tm = gTm * nTmG + li / nTnG;
    int tn = gTn * nTnG + li % nTnG;
    if (tn >= nTnTot) return;          // uniform early-exit, before any barrier

    const int rowBase = tm * 256, colBase = tn * 256;
    const int kbase = slice * ktiles;
    if (EPI == 0) Cf += (long long)slice * sliceC;
    if (EPI == 2) Cb += (long long)slice * sliceC;

    // staging geometry: lane -> row (lane>>3), phys k-slot (lane&7);
    // source k-slot pre-swizzled so reads XOR by (row&7).
    const int lr  = lane >> 3;
    const int skE = (((lane & 7) ^ (lr & 7)) << 3);
    const ushort_t* Bsrc = Bt + (size_t)(colBase + wave * 32 + lr) * ldb + skE;
    const ushort_t* Asrc = A + (size_t)(rowBase + wave * 32 + lr) * lda + skE;

    auto stageA = [&](int t) {
        ushort_t* d = &As[t & 1][wave * 32 * 64];
        if (AMODE == 0) {
            const ushort_t* s = Asrc + (size_t)(kbase + t) * 64;
            #pragma unroll
            for (int j = 0; j < 4; ++j)
                gload16(s + (size_t)(j * 8) * lda, d + j * 512);
        } else {
            int seg  = t >> 3;                                   // 8 k-tiles per 512-segment
            int dts  = (seg == 0) ? 0 : (seg == 1 ? (T_SEQ - 1) : 1);
            int colE = ((t & 7) << 6) + skE;
            #pragma unroll
            for (int j = 0; j < 4; ++j) {
                int gr = rowBase + wave * 32 + j * 8 + lr;
                int sr = (gr & ~(T_SEQ - 1)) | ((gr + dts) & (T_SEQ - 1));
                gload16(A + (size_t)sr * DM + colE, d + j * 512);
            }
        }
    };
    auto stageB = [&](int t) {
        ushort_t* d = &Bs[t % 3][wave * 32 * 64];
        const ushort_t* s = Bsrc + (size_t)(kbase + t) * 64;
        #pragma unroll
        for (int j = 0; j < 4; ++j)
            gload16(s + (size_t)(j * 8) * ldb, d + j * 512);
    };

    // MFMA fragment read geometry
    const int l15 = lane & 15;
    const int sl0 = (((lane >> 4) ^ (lane & 7))) << 3;       // kstep0 slot offset (elems)
    const int sl1 = (((lane >> 4) + 4) ^ (lane & 7)) << 3;   // kstep1
    const int aoff = (wm * 128 + l15) * 64;
    const int boff = (wn * 64 + l15) * 64;

    f32x4 acc[8][4] = {};
    bf16x8 Ar[2][2][4];     // [mh][kstep][m] — full tile's A frags
    bf16x8 Br[2][2][2];     // [nh][kstep][n]

    auto readAall = [&](int buf) {
        #pragma unroll
        for (int mh = 0; mh < 2; ++mh)
            #pragma unroll
            for (int m = 0; m < 4; ++m) {
                int base = aoff + mh * 4096 + m * 1024;
                Ar[mh][0][m] = *(const bf16x8*)&As[buf][base + sl0];
                Ar[mh][1][m] = *(const bf16x8*)&As[buf][base + sl1];
            }
    };
    auto readB = [&](int buf3, int nh) {
        #pragma unroll
        for (int n = 0; n < 2; ++n) {
            int base = boff + nh * 2048 + n * 1024;
            Br[nh][0][n] = *(const bf16x8*)&Bs[buf3][base + sl0];
            Br[nh][1][n] = *(const bf16x8*)&Bs[buf3][base + sl1];
        }
    };
    auto mmaQ = [&](int mh, int nh) {
        #pragma unroll
        for (int k = 0; k < 2; ++k)
            #pragma unroll
            for (int m = 0; m < 4; ++m)
                #pragma unroll
                for (int n = 0; n < 2; ++n)
                    acc[mh * 4 + m][nh * 2 + n] = __builtin_amdgcn_mfma_f32_16x16x32_bf16(
                        Ar[mh][k][m], Br[nh][k][n], acc[mh * 4 + m][nh * 2 + n], 0, 0, 0);
    };

    // prologue: A0,B0 + A1,B1 in flight; wait A0,B0 (oldest 8)
    stageA(0); stageB(0);
    if (ktiles > 1) { stageA(1); stageB(1); VMCNT8(); } else { VMCNT0(); }
    BAR();

    for (int t = 0; t < ktiles; ++t) {
        const int curA = t & 1;
        const int curB = t % 3;
        const bool pre = (t + 2 < ktiles);
        // P1: all A frags + B(nh0); deep-prefetch B(t+2) -> Bs[(t+2)%3]
        readAall(curA); readB(curB, 0);
        if (pre) stageB(t + 2);
        BAR();
        __builtin_amdgcn_s_setprio(1); mmaQ(0, 0); __builtin_amdgcn_s_setprio(0);
        BAR();
        // P2: B(nh1); prefetch A(t+2) -> As[curA] (all As[curA] reads retired in P1)
        readB(curB, 1);
        if (pre) stageA(t + 2);
        BAR();
        __builtin_amdgcn_s_setprio(1); mmaQ(0, 1); __builtin_amdgcn_s_setprio(0);
        BAR();
        // P3: pure MFMA cluster; counted vmcnt (waits A(t+1),B(t+1) exactly)
        __builtin_amdgcn_s_setprio(1); mmaQ(1, 1); mmaQ(1, 0); __builtin_amdgcn_s_setprio(0);
        if (pre) { VMCNT8(); } else { VMCNT0(); }
        BAR();
    }

    // epilogue
    const int cl = l15, rl = (lane >> 4) << 2;
    if constexpr (EPI == 0) {
        #pragma unroll
        for (int mf = 0; mf < 8; ++mf) {
            int gr = rowBase + wm * 128 + mf * 16 + rl;
            #pragma unroll
            for (int nf = 0; nf < 4; ++nf) {
                int gc = colBase + wn * 64 + nf * 16 + cl;
                #pragma unroll
                for (int i = 0; i < 4; ++i)
                    Cf[(size_t)(gr + i) * ldc + gc] = acc[mf][nf][i];
            }
        }
    } else if constexpr (EPI == 2) {
        #pragma unroll
        for (int mf = 0; mf < 8; ++mf) {
            int gr = rowBase + wm * 128 + mf * 16 + rl;
            #pragma unroll
            for (int nf = 0; nf < 4; ++nf) {
                int gc = colBase + wn * 64 + nf * 16 + cl;
                #pragma unroll
                for (int i = 0; i < 4; ++i)
                    Cb[(size_t)(gr + i) * ldc + gc] = f2bf(acc[mf][nf][i]);
            }
        }
    } else {
        int r = (colBase + wn * 64) >> 10;   // 64-col span never crosses a rule boundary
        float bv[4];
        #pragma unroll
        for (int nf = 0; nf < 4; ++nf)
            bv[nf] = bias[r * H2 + ((colBase + wn * 64 + nf * 16 + cl) & (H2 - 1))];
        #pragma unroll
        for (int mf = 0; mf < 8; ++mf) {
            int gr = rowBase + wm * 128 + mf * 16 + rl;
            #pragma unroll
            for (int i = 0; i < 4; ++i) {
                float rwv = rwp[((gr + i) & (T_SEQ - 1)) * NR + r];
                #pragma unroll
                for (int nf = 0; nf < 4; ++nf) {
                    int gc = colBase + wn * 64 + nf * 16 + cl;
                    float v = acc[mf][nf][i] + bv[nf];
                    v = gelu_fast(v) * rwv;
                    Cb[(size_t)(gr + i) * ldc + gc] = f2bf(v);
                }
            }
        }
    }
}

extern "C" void kernel_launch(void* const* d_in, const int* in_sizes, int n_in,
                              void* d_out, int out_size, void* d_ws, size_t ws_size,
                              hipStream_t stream)
{
    const int*   tokens = (const int*)d_in[0];
    const float* gate   = (const float*)d_in[1];
    const float* emb    = (const float*)d_in[2];
    const float* pos    = (const float*)d_in[3];
    const float* w1     = (const float*)d_in[4];
    const float* b1     = (const float*)d_in[5];
    const float* w2     = (const float*)d_in[6];
    const float* b2     = (const float*)d_in[7];
    const float* selw   = (const float*)d_in[8];
    const float* selb   = (const float*)d_in[9];
    const float* ng     = (const float*)d_in[10];
    const float* nbm    = (const float*)d_in[11];
    const float* lnfg   = (const float*)d_in[12];
    const float* lnfb   = (const float*)d_in[13];
    const float* headw  = (const float*)d_in[14];
    float* out = (float*)d_out;
    (void)in_sizes; (void)n_in; (void)out_size; (void)ws_size;

    size_t off = 0;
    auto alloc = [&](size_t bytes) {
        void* p = (char*)d_ws + off;
        off += (bytes + 255) & ~(size_t)255;
        return p;
    };
    float*    x    = (float*)alloc((size_t)BT * DM * 4);
    ushort_t* xbf  = (ushort_t*)alloc((size_t)BT * DM * 2);
    ushort_t* evp  = (ushort_t*)alloc((size_t)4 * BT * DM * 2);
    ushort_t* W1t  = (ushort_t*)alloc((size_t)NR * H2 * K1 * 2);
    ushort_t* W2t  = (ushort_t*)alloc((size_t)DM * HN * 2);
    ushort_t* HWt  = (ushort_t*)alloc((size_t)VSZ * DM * 2);
    float*    rw   = (float*)alloc((size_t)T_SEQ * NR * 4);
    float*    b2rw = (float*)alloc((size_t)T_SEQ * DM * 4);
    ushort_t* H    = (ushort_t*)alloc((size_t)BT * HN * 2);

    // --- weight conversion / transpose ---
    transpose_f32_bf16<<<dim3(H2 / 32, K1 / 32, NR), dim3(32, 8), 0, stream>>>(
        w1, W1t, K1, H2, (long long)K1 * H2, (long long)H2 * K1, K1);
    transpose_f32_bf16<<<dim3(DM / 32, H2 / 32, NR), dim3(32, 8), 0, stream>>>(
        w2, W2t, H2, DM, (long long)H2 * DM, (long long)H2, HN);
    transpose_f32_bf16<<<dim3(VSZ / 32, DM / 32, 1), dim3(32, 8), 0, stream>>>(
        headw, HWt, DM, VSZ, 0LL, 0LL, DM);

    // --- x = embed + pos (f32 + bf16); rule weights + b2rw table ---
    embed_pos<<<dim3(BT), dim3(256), 0, stream>>>(tokens, emb, pos, x, xbf);
    rw_kernel<<<dim3(T_SEQ), dim3(64), 0, stream>>>(gate, selw, selb, b2, rw, b2rw);

    // --- 5 CA steps ---
    for (int s = 0; s < NSTEP; ++s) {
        // GEMM1: H = bf16(gelu(NB @ W1 + b1) * rw); groups: tn-shared per XCD (32x1)
        gemm8<1, 1><<<dim3(1024), dim3(512), 0, stream>>>(
            xbf, W1t, nullptr, H, /*nTmG*/32, /*nTnG*/1, /*gridTn*/32,
            /*nPerSlice*/1024, /*ktiles*/K1 / 64, /*nTnTot*/32,
            DM, K1, HN, 0LL, b1, rw);
        // GEMM2: evp[slice] = bf16(H @ W2) (split-K x4); 32x2 group
        gemm8<2, 0><<<dim3(256), dim3(512), 0, stream>>>(
            H, W2t, nullptr, evp, /*nTmG*/32, /*nTnG*/2, /*gridTn*/1,
            /*nPerSlice*/64, /*ktiles*/HN / 64 / 4, /*nTnTot*/2,
            HN, HN, DM, (long long)BT * DM, nullptr, nullptr);
        if (s < NSTEP - 1) {
            ln_kernel<0><<<dim3(BT / 4), dim3(256), 0, stream>>>(
                x, evp, b2rw, ng + s * DM, nbm + s * DM, nullptr, nullptr, x, xbf);
        } else {
            // fused: step-5 LN + final LN -> xbf (x5 never materialized)
            ln_kernel<2><<<dim3(BT / 4), dim3(256), 0, stream>>>(
                x, evp, b2rw, ng + s * DM, nbm + s * DM, lnfg, lnfb, nullptr, xbf);
        }
    }

    // --- head GEMM -> f32 out; 8x4 groups (A 2MB + B 1MB per XCD round, L2-fit) ---
    gemm8<0, 0><<<dim3(4096), dim3(512), 0, stream>>>(
        xbf, HWt, out, nullptr, /*nTmG*/8, /*nTnG*/4, /*gridTn*/32,
        /*nPerSlice*/4096, /*ktiles*/DM / 64, /*nTnTot*/125,
        DM, DM, VSZ, 0LL, nullptr, nullptr);
}